// Round 3
// baseline (309.213 us; speedup 1.0000x reference)
//
#include <hip/hip_runtime.h>

// Problem constants
#define BATCH 4
#define SEQ 2048
#define DM 1024
#define NH 16
#define DK 64

typedef unsigned short u16;
typedef unsigned int u32;
typedef __attribute__((ext_vector_type(8))) short bfrag;    // 8 bf16 (MFMA x32 A/B)
typedef __attribute__((ext_vector_type(4))) short bfrag4;   // 4 bf16 (MFMA x16 A/B)
typedef __attribute__((ext_vector_type(4))) float ffrag;    // 4 fp32 (MFMA C/D)

__device__ inline u16 f2bf(float f) {
  union { float f; u32 u; } v; v.f = f;
  u32 u = v.u;
  return (u16)((u + 0x7FFFu + ((u >> 16) & 1u)) >> 16);  // RNE
}
__device__ inline float bf2f(u16 u) {
  union { u32 u; float f; } v; v.u = ((u32)u) << 16;
  return v.f;
}
__device__ inline ffrag MFMA(bfrag a, bfrag b, ffrag c) {
  return __builtin_amdgcn_mfma_f32_16x16x32_bf16(a, b, c, 0, 0, 0);
}
// Device pass only (host __has_builtin is false — R4 lesson). Host gets a stub.
#if defined(__has_builtin)
#if __has_builtin(__builtin_amdgcn_mfma_f32_16x16x16bf16_1k)
#define HAVE_MFMA16 1
#endif
#endif
#if HAVE_MFMA16
__device__ inline ffrag MFMA16(bfrag4 a, bfrag4 b, ffrag c) {
  return __builtin_amdgcn_mfma_f32_16x16x16bf16_1k(a, b, c, 0, 0, 0);
}
#else
__device__ inline ffrag MFMA16(bfrag4 a, bfrag4 b, ffrag c) { return c; }  // host stub
#endif

// async global -> LDS, 16 bytes per lane (wave-uniform base + lane*16)
__device__ __forceinline__ void g2l16(const u16* g, u16* l) {
  __builtin_amdgcn_global_load_lds(
      (const __attribute__((address_space(1))) u16*)g,
      (__attribute__((address_space(3))) u16*)l, 16, 0, 0);
}

// ---------------- fused fp32 -> bf16 conversion (x + 4 weights, one launch).
// blocks [0,8192): x (8M floats). blocks [8192,12288): weights, 1024 blocks each.
__global__ __launch_bounds__(256) void cvt_all(
    const float* __restrict__ x,
    const float* __restrict__ a, const float* __restrict__ b,
    const float* __restrict__ c, const float* __restrict__ d,
    u16* __restrict__ ox,
    u16* __restrict__ oa, u16* __restrict__ ob,
    u16* __restrict__ oc, u16* __restrict__ od) {
  int blk = blockIdx.x;
  const float* in;
  u16* out;
  int i;
  if (blk < 8192) {
    in = x; out = ox; i = blk * 256 + threadIdx.x;
  } else {
    int wb = blk - 8192;
    int which = wb >> 10;
    in = which == 0 ? a : which == 1 ? b : which == 2 ? c : d;
    out = which == 0 ? oa : which == 1 ? ob : which == 2 ? oc : od;
    i = (wb & 1023) * 256 + threadIdx.x;
  }
  float4 v = ((const float4*)in)[i];
  union { u16 u[4]; uint2 dd; } o;
  o.u[0] = f2bf(v.x); o.u[1] = f2bf(v.y); o.u[2] = f2bf(v.z); o.u[3] = f2bf(v.w);
  ((uint2*)out)[i] = o.dd;
}

// ---------------- fused Q/K/V projection. z=0: Q row-layout [B,H,S,DK].
// z=1: K swizzled per 64-kv tile: frag (j=(s>>4)&3, half=d>>5) for lane
// (quad=(d>>3)&3, l15=s&15) at ((j*2+half)*64 + quad*16 + l15)*8 + (d&7).
// z=2: V^T swizzled (computed with swapped operand roles): element (d,s) at
// unit=((d>>4)*4+((s>>4)&3))*64 + ((s>>2)&3)*16 + (d&15), offset unit*4+(s&3).
// Both swizzles are the exact lane-linear images attn's fragments read, so
// attn can stage them with pure g2l16 DMA and read conflict-free.
__global__ __launch_bounds__(256) void gemm_qkv(
    const u16* __restrict__ xb,
    const u16* __restrict__ Wq, const u16* __restrict__ Wk,
    const u16* __restrict__ Wv,
    u16* __restrict__ Qb, u16* __restrict__ Ksw, u16* __restrict__ Vsw) {
  const int z = blockIdx.z;
  const u16* Bm = z == 0 ? Wq : z == 1 ? Wk : Wv;

  const int K = DM;
  const int bm = blockIdx.y * 128, bn = blockIdx.x * 128;
  __shared__ __align__(16) u16 As[128 * 32];
  __shared__ __align__(16) u16 Bs[128 * 32];
  const int tid = threadIdx.x;
  const int lane = tid & 63;
  const int w = tid >> 6;
  const int wr = w >> 1, wc = w & 1;
  const int l15 = lane & 15, quad = lane >> 4;
  const int srow = tid >> 2, scol = (tid & 3) * 8;

  ffrag acc[4][4] = {};

  for (int k0 = 0; k0 < K; k0 += 32) {
    __syncthreads();
    g2l16(&xb[(size_t)(bm + srow) * K + k0 + scol], &As[tid * 8]);
    g2l16(&xb[(size_t)(bm + 64 + srow) * K + k0 + scol], &As[(tid + 256) * 8]);
    g2l16(&Bm[(size_t)(bn + srow) * K + k0 + scol], &Bs[tid * 8]);
    g2l16(&Bm[(size_t)(bn + 64 + srow) * K + k0 + scol], &Bs[(tid + 256) * 8]);
    __syncthreads();
    bfrag af[4], bf[4];
    if (z < 2) {
#pragma unroll
      for (int i = 0; i < 4; i++)
        af[i] = *(const bfrag*)(&As[(wr * 64 + i * 16 + l15) * 32 + quad * 8]);
#pragma unroll
      for (int j = 0; j < 4; j++)
        bf[j] = *(const bfrag*)(&Bs[(wc * 64 + j * 16 + l15) * 32 + quad * 8]);
    } else {   // V: A = W (out-dims as m), B = x^T (tokens as n)
#pragma unroll
      for (int i = 0; i < 4; i++)
        af[i] = *(const bfrag*)(&Bs[(wr * 64 + i * 16 + l15) * 32 + quad * 8]);
#pragma unroll
      for (int j = 0; j < 4; j++)
        bf[j] = *(const bfrag*)(&As[(wc * 64 + j * 16 + l15) * 32 + quad * 8]);
    }
#pragma unroll
    for (int i = 0; i < 4; i++)
#pragma unroll
      for (int j = 0; j < 4; j++)
        acc[i][j] = MFMA(af[i], bf[j], acc[i][j]);
  }

  if (z == 0) {
#pragma unroll
    for (int i = 0; i < 4; i++)
#pragma unroll
      for (int j = 0; j < 4; j++)
#pragma unroll
        for (int r = 0; r < 4; r++) {
          int m = bm + wr * 64 + i * 16 + quad * 4 + r;
          int n = bn + wc * 64 + j * 16 + l15;
          int b = m >> 11, s = m & 2047;
          int h = n >> 6, d = n & 63;
          Qb[(((size_t)(b * NH + h)) * SEQ + s) * DK + d] = f2bf(acc[i][j][r]);
        }
  } else if (z == 1) {
#pragma unroll
    for (int i = 0; i < 4; i++)
#pragma unroll
      for (int j = 0; j < 4; j++)
#pragma unroll
        for (int r = 0; r < 4; r++) {
          int m = bm + wr * 64 + i * 16 + quad * 4 + r;
          int n = bn + wc * 64 + j * 16 + l15;
          int b = m >> 11, s = m & 2047;
          int h = n >> 6, d = n & 63;
          size_t hb = (size_t)(b * NH + h) * (SEQ * DK);
          size_t off = hb + (size_t)(s >> 6) * 4096 +
              ((((s >> 4) & 3) * 2 + (d >> 5)) * 64 +
               ((d >> 3) & 3) * 16 + (s & 15)) * 8 + (d & 7);
          Ksw[off] = f2bf(acc[i][j][r]);
        }
  } else {
#pragma unroll
    for (int i = 0; i < 4; i++)
#pragma unroll
      for (int j = 0; j < 4; j++)
#pragma unroll
        for (int r = 0; r < 4; r++) {
          int n = bn + wr * 64 + i * 16 + quad * 4 + r;   // out-dim
          int m = bm + wc * 64 + j * 16 + l15;            // token
          int b = m >> 11, s = m & 2047;
          int h = n >> 6, d = n & 63;
          size_t hb = (size_t)(b * NH + h) * (SEQ * DK);
          size_t off = hb + (size_t)(s >> 6) * 4096 +
              ((((d >> 4) * 4 + ((s >> 4) & 3)) * 64 +
                ((s >> 2) & 3) * 16 + (d & 15)) * 4 + (s & 3));
          Vsw[off] = f2bf(acc[i][j][r]);
        }
  }
}

// ---------------- out projection GEMM: out = Ab @ Wout^T, fp32 output
__global__ __launch_bounds__(256) void gemm_out(
    const u16* __restrict__ Ab, const u16* __restrict__ Wo, float* __restrict__ C) {
  const int K = DM, N = DM;
  const int bm = blockIdx.y * 128, bn = blockIdx.x * 128;
  __shared__ __align__(16) u16 As[128 * 32];
  __shared__ __align__(16) u16 Bs[128 * 32];
  const int tid = threadIdx.x;
  const int lane = tid & 63;
  const int w = tid >> 6;
  const int wr = w >> 1, wc = w & 1;
  const int l15 = lane & 15, quad = lane >> 4;
  const int srow = tid >> 2, scol = (tid & 3) * 8;

  ffrag acc[4][4] = {};

  for (int k0 = 0; k0 < K; k0 += 32) {
    __syncthreads();
    g2l16(&Ab[(size_t)(bm + srow) * K + k0 + scol], &As[tid * 8]);
    g2l16(&Ab[(size_t)(bm + 64 + srow) * K + k0 + scol], &As[(tid + 256) * 8]);
    g2l16(&Wo[(size_t)(bn + srow) * K + k0 + scol], &Bs[tid * 8]);
    g2l16(&Wo[(size_t)(bn + 64 + srow) * K + k0 + scol], &Bs[(tid + 256) * 8]);
    __syncthreads();
    bfrag af[4], bf[4];
#pragma unroll
    for (int i = 0; i < 4; i++)
      af[i] = *(const bfrag*)(&As[(wr * 64 + i * 16 + l15) * 32 + quad * 8]);
#pragma unroll
    for (int j = 0; j < 4; j++)
      bf[j] = *(const bfrag*)(&Bs[(wc * 64 + j * 16 + l15) * 32 + quad * 8]);
#pragma unroll
    for (int i = 0; i < 4; i++)
#pragma unroll
      for (int j = 0; j < 4; j++)
        acc[i][j] = MFMA(af[i], bf[j], acc[i][j]);
  }

#pragma unroll
  for (int i = 0; i < 4; i++)
#pragma unroll
    for (int j = 0; j < 4; j++)
#pragma unroll
      for (int r = 0; r < 4; r++) {
        int m = bm + wr * 64 + i * 16 + quad * 4 + r;
        int n = bn + wc * 64 + j * 16 + l15;
        C[(size_t)m * N + n] = acc[i][j][r];
      }
}

// ---------------- Flash attention (R3: 64 q-rows/block + MFMA lsum; NO cvtpk).
// Grid (SEQ/64, B*H) = 2048 blocks -> 5 resident/CU (32KB LDS), 8 queued.
// Each wave owns one 16-q block. S^T = K.Q^T (x32 MFMA); P truncated to bf16
// via bit-ops (finite by construction — R2's cvtpk asm produced NaN garbage);
// lsum computed ON THE MFMA PIPE as ones.P^T (sums the exact bf16 P the PV
// MFMA consumes -> rounding-consistent; C-layout replicates the sum to every
// lane: no shuffle reduce). O^T += V^T.P^T (x16 MFMA). K/V staged via g2l16
// DMA from swizzled global into double buffers; compute reads ONLY LDS
// (single per-tile barrier; DMA of t+1 overlaps all of compute(t)).
// T5 setprio around compute.
__global__ __launch_bounds__(256) void attn(
    const u16* __restrict__ Qb, const u16* __restrict__ Ksw,
    const u16* __restrict__ Vsw, u16* __restrict__ Ab) {
  const int bh = blockIdx.y;
  const int b = bh >> 4, h = bh & 15;
  const int qbase = blockIdx.x * 64;
  const int tid = threadIdx.x;
  const int w = tid >> 6, lane = tid & 63;
  const int l15 = lane & 15, quad = lane >> 4;

  __shared__ __align__(16) u16 Kt[2][4096];   // swizzled 64x64 K tile, dbuf
  __shared__ __align__(16) u16 Vt[2][4096];   // swizzled 64x64 V tile, dbuf

  const size_t hbase = (size_t)bh * SEQ * DK;

  // Q fragments (B-operand: n=q=l15, k=d=quad*8+e) scaled by 0.125*log2e
  const float qscale = 0.125f * 1.4426950408889634f;
  bfrag q[2];
#pragma unroll
  for (int kk = 0; kk < 2; kk++) {
    bfrag t = *(const bfrag*)(&Qb[hbase +
        (size_t)(qbase + w * 16 + l15) * DK + kk * 32 + quad * 8]);
#pragma unroll
    for (int e = 0; e < 8; e++)
      q[kk][e] = (short)f2bf(bf2f((u16)t[e]) * qscale);
  }

  const bfrag4 ones = {(short)0x3F80, (short)0x3F80, (short)0x3F80, (short)0x3F80};

  ffrag O[4] = {};     // O^T accs per d-block
  ffrag Ls = {};       // lsum acc (ones-matrix MFMA; all lanes get full sum)

  // prefetch tile 0 (K: 8KB = 2 DMA calls; V: 8KB = 2 DMA calls)
  {
    const u16* ks = &Ksw[hbase];
    const u16* vs = &Vsw[hbase];
    g2l16(&ks[tid * 8], &Kt[0][tid * 8]);
    g2l16(&ks[2048 + tid * 8], &Kt[0][2048 + tid * 8]);
    g2l16(&vs[tid * 8], &Vt[0][tid * 8]);
    g2l16(&vs[2048 + tid * 8], &Vt[0][2048 + tid * 8]);
  }

  for (int t = 0; t < SEQ / 64; t++) {
    const int buf = t & 1;
    __syncthreads();   // DMA for tile t complete; prior reads of buf^1 done
    if (t + 1 < SEQ / 64) {
      const u16* ks = &Ksw[hbase + (size_t)(t + 1) * 4096];
      const u16* vs = &Vsw[hbase + (size_t)(t + 1) * 4096];
      g2l16(&ks[tid * 8], &Kt[buf ^ 1][tid * 8]);
      g2l16(&ks[2048 + tid * 8], &Kt[buf ^ 1][2048 + tid * 8]);
      g2l16(&vs[tid * 8], &Vt[buf ^ 1][tid * 8]);
      g2l16(&vs[2048 + tid * 8], &Vt[buf ^ 1][2048 + tid * 8]);
    }

    __builtin_amdgcn_s_setprio(1);
    bfrag4 pb[4];
#pragma unroll
    for (int j = 0; j < 4; j++) {     // kv 16-block
      bfrag k0f = *(const bfrag*)(&Kt[buf][((j * 2 + 0) * 64 + lane) * 8]);
      bfrag k1f = *(const bfrag*)(&Kt[buf][((j * 2 + 1) * 64 + lane) * 8]);
      ffrag z = {};
      z = MFMA(k0f, q[0], z);
      z = MFMA(k1f, q[1], z);         // S^T block: lane (q=l15, s=quad*4+r)
      u32 u0 = __float_as_uint(__builtin_amdgcn_exp2f(z[0]));
      u32 u1 = __float_as_uint(__builtin_amdgcn_exp2f(z[1]));
      u32 u2 = __float_as_uint(__builtin_amdgcn_exp2f(z[2]));
      u32 u3 = __float_as_uint(__builtin_amdgcn_exp2f(z[3]));
      union { u32 d[2]; bfrag4 v; } pk;
      pk.d[0] = (u1 & 0xffff0000u) | (u0 >> 16);
      pk.d[1] = (u3 & 0xffff0000u) | (u2 >> 16);
      pb[j] = pk.v;
      Ls = MFMA16(ones, pb[j], Ls);   // lsum on the matrix pipe
    }

    // O^T += V^T . P^T : A-frags lane-linear b64 from swizzled V tile
#pragma unroll
    for (int j = 0; j < 4; j++)
#pragma unroll
      for (int db = 0; db < 4; db++) {
        bfrag4 vf = *(const bfrag4*)(&Vt[buf][((db * 4 + j) * 64 + lane) * 4]);
        O[db] = MFMA16(vf, pb[j], O[db]);
      }
    __builtin_amdgcn_s_setprio(0);
  }

  const float rl = 1.0f / Ls[0];

  // O^T C-layout: lane holds q=l15, d=quad*4+r. Pack 4 d (8B) per store.
  const size_t obase = ((size_t)b * SEQ) * DM + (size_t)h * DK;
  const int s = qbase + w * 16 + l15;
#pragma unroll
  for (int db = 0; db < 4; db++) {
    union { u16 u[4]; uint2 d; } o;
#pragma unroll
    for (int r = 0; r < 4; r++) o.u[r] = f2bf(O[db][r] * rl);
    *(uint2*)(&Ab[obase + (size_t)s * DM + db * 16 + quad * 4]) = o.d;
  }
}

extern "C" void kernel_launch(void* const* d_in, const int* in_sizes, int n_in,
                              void* d_out, int out_size, void* d_ws, size_t ws_size,
                              hipStream_t stream) {
  const float* x  = (const float*)d_in[0];
  const float* Wq = (const float*)d_in[1];
  const float* Wk = (const float*)d_in[2];
  const float* Wv = (const float*)d_in[3];
  const float* Wo = (const float*)d_in[4];
  float* out = (float*)d_out;

  char* ws = (char*)d_ws;
  u16* xb  = (u16*)(ws + 0);          // 16 MB
  u16* Wqb = (u16*)(ws + 16777216);
  u16* Wkb = (u16*)(ws + 18874368);
  u16* Wvb = (u16*)(ws + 20971520);
  u16* Wob = (u16*)(ws + 23068672);
  u16* Qb  = (u16*)(ws + 25165824);   // [B,H,S,DK]
  u16* Ksw = (u16*)(ws + 41943040);   // [B,H] x 32 tiles x swizzled 64x64
  u16* Vsw = (u16*)(ws + 58720256);   // [B,H] x 32 tiles x swizzled 64x64
  u16* Ab  = (u16*)(ws + 75497472);   // [B,S,DM]
  const size_t NEED = 92274688;
  if (ws_size < NEED) return;

  cvt_all<<<12288, 256, 0, stream>>>(x, Wq, Wk, Wv, Wo, xb, Wqb, Wkb, Wvb, Wob);

  dim3 gqkv(DM / 128, (BATCH * SEQ) / 128, 3);
  gemm_qkv<<<gqkv, 256, 0, stream>>>(xb, Wqb, Wkb, Wvb, Qb, Ksw, Vsw);

  dim3 gat(SEQ / 64, BATCH * NH);
  attn<<<gat, 256, 0, stream>>>(Qb, Ksw, Vsw, Ab);

  dim3 gout(DM / 128, (BATCH * SEQ) / 128);
  gemm_out<<<gout, 256, 0, stream>>>(Ab, Wob, out);
}

// Round 4
// 298.806 us; speedup vs baseline: 1.0348x; 1.0348x over previous
//
#include <hip/hip_runtime.h>

// Problem constants
#define BATCH 4
#define SEQ 2048
#define DM 1024
#define NH 16
#define DK 64

typedef unsigned short u16;
typedef unsigned int u32;
typedef __attribute__((ext_vector_type(8))) short bfrag;    // 8 bf16 (MFMA x32 A/B)
typedef __attribute__((ext_vector_type(4))) short bfrag4;   // 4 bf16 (MFMA x16 A/B)
typedef __attribute__((ext_vector_type(4))) float ffrag;    // 4 fp32 (MFMA C/D)

__device__ inline u16 f2bf(float f) {
  union { float f; u32 u; } v; v.f = f;
  u32 u = v.u;
  return (u16)((u + 0x7FFFu + ((u >> 16) & 1u)) >> 16);  // RNE
}
__device__ inline float bf2f(u16 u) {
  union { u32 u; float f; } v; v.u = ((u32)u) << 16;
  return v.f;
}
__device__ inline ffrag MFMA(bfrag a, bfrag b, ffrag c) {
  return __builtin_amdgcn_mfma_f32_16x16x32_bf16(a, b, c, 0, 0, 0);
}
// Device pass only (host __has_builtin is false — R4 lesson). Host gets a stub.
#if defined(__has_builtin)
#if __has_builtin(__builtin_amdgcn_mfma_f32_16x16x16bf16_1k)
#define HAVE_MFMA16 1
#endif
#endif
#if HAVE_MFMA16
__device__ inline ffrag MFMA16(bfrag4 a, bfrag4 b, ffrag c) {
  return __builtin_amdgcn_mfma_f32_16x16x16bf16_1k(a, b, c, 0, 0, 0);
}
#else
__device__ inline ffrag MFMA16(bfrag4 a, bfrag4 b, ffrag c) { return c; }  // host stub
#endif

// async global -> LDS, 16 bytes per lane (wave-uniform base + lane*16)
__device__ __forceinline__ void g2l16(const u16* g, u16* l) {
  __builtin_amdgcn_global_load_lds(
      (const __attribute__((address_space(1))) u16*)g,
      (__attribute__((address_space(3))) u16*)l, 16, 0, 0);
}

// ---------------- fused fp32 -> bf16 conversion (x + 4 weights, one launch).
// blocks [0,8192): x (8M floats). blocks [8192,12288): weights, 1024 blocks each.
__global__ __launch_bounds__(256) void cvt_all(
    const float* __restrict__ x,
    const float* __restrict__ a, const float* __restrict__ b,
    const float* __restrict__ c, const float* __restrict__ d,
    u16* __restrict__ ox,
    u16* __restrict__ oa, u16* __restrict__ ob,
    u16* __restrict__ oc, u16* __restrict__ od) {
  int blk = blockIdx.x;
  const float* in;
  u16* out;
  int i;
  if (blk < 8192) {
    in = x; out = ox; i = blk * 256 + threadIdx.x;
  } else {
    int wb = blk - 8192;
    int which = wb >> 10;
    in = which == 0 ? a : which == 1 ? b : which == 2 ? c : d;
    out = which == 0 ? oa : which == 1 ? ob : which == 2 ? oc : od;
    i = (wb & 1023) * 256 + threadIdx.x;
  }
  float4 v = ((const float4*)in)[i];
  union { u16 u[4]; uint2 dd; } o;
  o.u[0] = f2bf(v.x); o.u[1] = f2bf(v.y); o.u[2] = f2bf(v.z); o.u[3] = f2bf(v.w);
  ((uint2*)out)[i] = o.dd;
}

// ---------------- fused Q/K/V projection (R4: BK=64 + XOR-swizzled LDS).
// LDS tiles [128][64] bf16, linear dest for g2l16 (rule #21): the 16B slot
// within each 128B row is XOR-permuted on the GLOBAL SOURCE address
// (slot^(row&7) — per-thread constant) and the same involution is applied on
// the fragment ds_read address, so reads hit all 32 banks 2-way (free) instead
// of the 8-way conflict the old 64B-stride layout had. Barriers per K halved.
// z=0: Q row-layout [B,H,S,DK]. z=1: K swizzled per 64-kv tile. z=2: V^T
// swizzled (swapped operand roles). See epilogues.
__global__ __launch_bounds__(256) void gemm_qkv(
    const u16* __restrict__ xb,
    const u16* __restrict__ Wq, const u16* __restrict__ Wk,
    const u16* __restrict__ Wv,
    u16* __restrict__ Qb, u16* __restrict__ Ksw, u16* __restrict__ Vsw) {
  const int z = blockIdx.z;
  const u16* Bm = z == 0 ? Wq : z == 1 ? Wk : Wv;

  const int K = DM;
  const int bm = blockIdx.y * 128, bn = blockIdx.x * 128;
  __shared__ __align__(16) u16 As[128 * 64];
  __shared__ __align__(16) u16 Bs[128 * 64];
  const int tid = threadIdx.x;
  const int lane = tid & 63;
  const int w = tid >> 6;
  const int wr = w >> 1, wc = w & 1;
  const int l15 = lane & 15, quad = lane >> 4;
  // staging: call c covers rows [c*32, c*32+32); thread -> row c*32+(tid>>3),
  // LDS slot tid&7; source col slot^(row&7) (involution, per-thread constant)
  const int srow = tid >> 3;
  const int scol = (((tid & 7) ^ (srow & 7)) * 8);

  ffrag acc[4][4] = {};

  for (int k0 = 0; k0 < K; k0 += 64) {
    __syncthreads();
#pragma unroll
    for (int c = 0; c < 4; c++) {
      g2l16(&xb[(size_t)(bm + c * 32 + srow) * K + k0 + scol], &As[c * 2048 + tid * 8]);
      g2l16(&Bm[(size_t)(bn + c * 32 + srow) * K + k0 + scol], &Bs[c * 2048 + tid * 8]);
    }
    __syncthreads();
#pragma unroll
    for (int kk = 0; kk < 2; kk++) {
      bfrag af[4], bf[4];
      if (z < 2) {
#pragma unroll
        for (int i = 0; i < 4; i++)
          af[i] = *(const bfrag*)(&As[(wr * 64 + i * 16 + l15) * 64 +
                                      ((kk * 4 + quad) ^ (l15 & 7)) * 8]);
#pragma unroll
        for (int j = 0; j < 4; j++)
          bf[j] = *(const bfrag*)(&Bs[(wc * 64 + j * 16 + l15) * 64 +
                                      ((kk * 4 + quad) ^ (l15 & 7)) * 8]);
      } else {   // V: A = W (out-dims as m), B = x^T (tokens as n)
#pragma unroll
        for (int i = 0; i < 4; i++)
          af[i] = *(const bfrag*)(&Bs[(wr * 64 + i * 16 + l15) * 64 +
                                      ((kk * 4 + quad) ^ (l15 & 7)) * 8]);
#pragma unroll
        for (int j = 0; j < 4; j++)
          bf[j] = *(const bfrag*)(&As[(wc * 64 + j * 16 + l15) * 64 +
                                      ((kk * 4 + quad) ^ (l15 & 7)) * 8]);
      }
#pragma unroll
      for (int i = 0; i < 4; i++)
#pragma unroll
        for (int j = 0; j < 4; j++)
          acc[i][j] = MFMA(af[i], bf[j], acc[i][j]);
    }
  }

  if (z == 0) {
#pragma unroll
    for (int i = 0; i < 4; i++)
#pragma unroll
      for (int j = 0; j < 4; j++)
#pragma unroll
        for (int r = 0; r < 4; r++) {
          int m = bm + wr * 64 + i * 16 + quad * 4 + r;
          int n = bn + wc * 64 + j * 16 + l15;
          int b = m >> 11, s = m & 2047;
          int h = n >> 6, d = n & 63;
          Qb[(((size_t)(b * NH + h)) * SEQ + s) * DK + d] = f2bf(acc[i][j][r]);
        }
  } else if (z == 1) {
#pragma unroll
    for (int i = 0; i < 4; i++)
#pragma unroll
      for (int j = 0; j < 4; j++)
#pragma unroll
        for (int r = 0; r < 4; r++) {
          int m = bm + wr * 64 + i * 16 + quad * 4 + r;
          int n = bn + wc * 64 + j * 16 + l15;
          int b = m >> 11, s = m & 2047;
          int h = n >> 6, d = n & 63;
          size_t hb = (size_t)(b * NH + h) * (SEQ * DK);
          size_t off = hb + (size_t)(s >> 6) * 4096 +
              ((((s >> 4) & 3) * 2 + (d >> 5)) * 64 +
               ((d >> 3) & 3) * 16 + (s & 15)) * 8 + (d & 7);
          Ksw[off] = f2bf(acc[i][j][r]);
        }
  } else {
#pragma unroll
    for (int i = 0; i < 4; i++)
#pragma unroll
      for (int j = 0; j < 4; j++)
#pragma unroll
        for (int r = 0; r < 4; r++) {
          int n = bn + wr * 64 + i * 16 + quad * 4 + r;   // out-dim
          int m = bm + wc * 64 + j * 16 + l15;            // token
          int b = m >> 11, s = m & 2047;
          int h = n >> 6, d = n & 63;
          size_t hb = (size_t)(b * NH + h) * (SEQ * DK);
          size_t off = hb + (size_t)(s >> 6) * 4096 +
              ((((d >> 4) * 4 + ((s >> 4) & 3)) * 64 +
                ((s >> 2) & 3) * 16 + (d & 15)) * 4 + (s & 3));
          Vsw[off] = f2bf(acc[i][j][r]);
        }
  }
}

// ---------------- out projection GEMM (R4: BK=64 + XOR swizzle, as above)
__global__ __launch_bounds__(256) void gemm_out(
    const u16* __restrict__ Ab, const u16* __restrict__ Wo, float* __restrict__ C) {
  const int K = DM, N = DM;
  const int bm = blockIdx.y * 128, bn = blockIdx.x * 128;
  __shared__ __align__(16) u16 As[128 * 64];
  __shared__ __align__(16) u16 Bs[128 * 64];
  const int tid = threadIdx.x;
  const int lane = tid & 63;
  const int w = tid >> 6;
  const int wr = w >> 1, wc = w & 1;
  const int l15 = lane & 15, quad = lane >> 4;
  const int srow = tid >> 3;
  const int scol = (((tid & 7) ^ (srow & 7)) * 8);

  ffrag acc[4][4] = {};

  for (int k0 = 0; k0 < K; k0 += 64) {
    __syncthreads();
#pragma unroll
    for (int c = 0; c < 4; c++) {
      g2l16(&Ab[(size_t)(bm + c * 32 + srow) * K + k0 + scol], &As[c * 2048 + tid * 8]);
      g2l16(&Wo[(size_t)(bn + c * 32 + srow) * K + k0 + scol], &Bs[c * 2048 + tid * 8]);
    }
    __syncthreads();
#pragma unroll
    for (int kk = 0; kk < 2; kk++) {
      bfrag af[4], bf[4];
#pragma unroll
      for (int i = 0; i < 4; i++)
        af[i] = *(const bfrag*)(&As[(wr * 64 + i * 16 + l15) * 64 +
                                    ((kk * 4 + quad) ^ (l15 & 7)) * 8]);
#pragma unroll
      for (int j = 0; j < 4; j++)
        bf[j] = *(const bfrag*)(&Bs[(wc * 64 + j * 16 + l15) * 64 +
                                    ((kk * 4 + quad) ^ (l15 & 7)) * 8]);
#pragma unroll
      for (int i = 0; i < 4; i++)
#pragma unroll
        for (int j = 0; j < 4; j++)
          acc[i][j] = MFMA(af[i], bf[j], acc[i][j]);
    }
  }

#pragma unroll
  for (int i = 0; i < 4; i++)
#pragma unroll
    for (int j = 0; j < 4; j++)
#pragma unroll
      for (int r = 0; r < 4; r++) {
        int m = bm + wr * 64 + i * 16 + quad * 4 + r;
        int n = bn + wc * 64 + j * 16 + l15;
        C[(size_t)m * N + n] = acc[i][j][r];
      }
}

// ---------------- Flash attention (R4: back to 128 q-rows/block (R1 geometry
// — R3's 64-row split doubled per-score LDS/staging work and regressed),
// keeping R3's verified MFMA-lsum and adding an XCD-locality grid transpose:
// blockIdx.x = head, so all 16 q-chunks of a head share one XCD's L2
// (per-XCD KV working set 64 MB -> 8 MB).
// Each wave owns two 16-q blocks. S^T = K.Q^T (x32 MFMA); P truncated to bf16
// via bit-ops; lsum on the MFMA pipe as ones.P^T (sums the exact bf16 P the
// PV MFMA consumes; C-layout broadcasts the sum to every lane -> no shuffle).
// O^T += V^T.P^T (x16 MFMA). K/V staged via g2l16 DMA from swizzled global
// into double buffers; compute reads ONLY LDS. T5 setprio around compute.
__global__ __launch_bounds__(256) void attn(
    const u16* __restrict__ Qb, const u16* __restrict__ Ksw,
    const u16* __restrict__ Vsw, u16* __restrict__ Ab) {
  const int bh = blockIdx.x;
  const int b = bh >> 4, h = bh & 15;
  const int qbase = blockIdx.y * 128;
  const int tid = threadIdx.x;
  const int w = tid >> 6, lane = tid & 63;
  const int l15 = lane & 15, quad = lane >> 4;

  __shared__ __align__(16) u16 Kt[2][4096];   // swizzled 64x64 K tile, dbuf
  __shared__ __align__(16) u16 Vt[2][4096];   // swizzled 64x64 V tile, dbuf

  const size_t hbase = (size_t)bh * SEQ * DK;

  // Q fragments (B-operand: n=q=l15, k=d=quad*8+e) scaled by 0.125*log2e
  const float qscale = 0.125f * 1.4426950408889634f;
  bfrag q[2][2];
#pragma unroll
  for (int i = 0; i < 2; i++)
#pragma unroll
    for (int kk = 0; kk < 2; kk++) {
      bfrag t = *(const bfrag*)(&Qb[hbase +
          (size_t)(qbase + w * 32 + i * 16 + l15) * DK + kk * 32 + quad * 8]);
#pragma unroll
      for (int e = 0; e < 8; e++)
        q[i][kk][e] = (short)f2bf(bf2f((u16)t[e]) * qscale);
    }

  const bfrag4 ones = {(short)0x3F80, (short)0x3F80, (short)0x3F80, (short)0x3F80};

  ffrag O[4][2] = {};      // O^T accs: [d-block][q-block]
  ffrag Ls[2] = {};        // lsum accs (ones-matrix MFMA; sum broadcast to lanes)

  // prefetch tile 0 (K: 8KB = 2 DMA calls; V: 8KB = 2 DMA calls)
  {
    const u16* ks = &Ksw[hbase];
    const u16* vs = &Vsw[hbase];
    g2l16(&ks[tid * 8], &Kt[0][tid * 8]);
    g2l16(&ks[2048 + tid * 8], &Kt[0][2048 + tid * 8]);
    g2l16(&vs[tid * 8], &Vt[0][tid * 8]);
    g2l16(&vs[2048 + tid * 8], &Vt[0][2048 + tid * 8]);
  }

  for (int t = 0; t < SEQ / 64; t++) {
    const int buf = t & 1;
    __syncthreads();   // DMA for tile t complete; prior reads of buf^1 done
    if (t + 1 < SEQ / 64) {
      const u16* ks = &Ksw[hbase + (size_t)(t + 1) * 4096];
      const u16* vs = &Vsw[hbase + (size_t)(t + 1) * 4096];
      g2l16(&ks[tid * 8], &Kt[buf ^ 1][tid * 8]);
      g2l16(&ks[2048 + tid * 8], &Kt[buf ^ 1][2048 + tid * 8]);
      g2l16(&vs[tid * 8], &Vt[buf ^ 1][tid * 8]);
      g2l16(&vs[2048 + tid * 8], &Vt[buf ^ 1][2048 + tid * 8]);
    }

    __builtin_amdgcn_s_setprio(1);
    bfrag4 pb[4][2];
#pragma unroll
    for (int j = 0; j < 4; j++) {     // kv 16-block
      bfrag k0f = *(const bfrag*)(&Kt[buf][((j * 2 + 0) * 64 + lane) * 8]);
      bfrag k1f = *(const bfrag*)(&Kt[buf][((j * 2 + 1) * 64 + lane) * 8]);
#pragma unroll
      for (int i = 0; i < 2; i++) {   // q 16-block
        ffrag z = {};
        z = MFMA(k0f, q[i][0], z);
        z = MFMA(k1f, q[i][1], z);    // S^T block: lane (q=l15, s=quad*4+r)
        u32 u0 = __float_as_uint(__builtin_amdgcn_exp2f(z[0]));
        u32 u1 = __float_as_uint(__builtin_amdgcn_exp2f(z[1]));
        u32 u2 = __float_as_uint(__builtin_amdgcn_exp2f(z[2]));
        u32 u3 = __float_as_uint(__builtin_amdgcn_exp2f(z[3]));
        union { u32 d[2]; bfrag4 v; } pk;
        pk.d[0] = (u1 & 0xffff0000u) | (u0 >> 16);
        pk.d[1] = (u3 & 0xffff0000u) | (u2 >> 16);
        pb[j][i] = pk.v;
        Ls[i] = MFMA16(ones, pb[j][i], Ls[i]);   // lsum on the matrix pipe
      }
    }

    // O^T += V^T . P^T : A-frags lane-linear b64 from swizzled V tile
#pragma unroll
    for (int j = 0; j < 4; j++)
#pragma unroll
      for (int db = 0; db < 4; db++) {
        bfrag4 vf = *(const bfrag4*)(&Vt[buf][((db * 4 + j) * 64 + lane) * 4]);
        O[db][0] = MFMA16(vf, pb[j][0], O[db][0]);
        O[db][1] = MFMA16(vf, pb[j][1], O[db][1]);
      }
    __builtin_amdgcn_s_setprio(0);
  }

  const float rl[2] = {1.0f / Ls[0][0], 1.0f / Ls[1][0]};

  // O^T C-layout: lane holds q=l15, d=quad*4+r. Pack 4 d (8B) per store.
  const size_t obase = ((size_t)b * SEQ) * DM + (size_t)h * DK;
#pragma unroll
  for (int db = 0; db < 4; db++)
#pragma unroll
    for (int i = 0; i < 2; i++) {
      int s = qbase + w * 32 + i * 16 + l15;
      union { u16 u[4]; uint2 d; } o;
#pragma unroll
      for (int r = 0; r < 4; r++) o.u[r] = f2bf(O[db][i][r] * rl[i]);
      *(uint2*)(&Ab[obase + (size_t)s * DM + db * 16 + quad * 4]) = o.d;
    }
}

extern "C" void kernel_launch(void* const* d_in, const int* in_sizes, int n_in,
                              void* d_out, int out_size, void* d_ws, size_t ws_size,
                              hipStream_t stream) {
  const float* x  = (const float*)d_in[0];
  const float* Wq = (const float*)d_in[1];
  const float* Wk = (const float*)d_in[2];
  const float* Wv = (const float*)d_in[3];
  const float* Wo = (const float*)d_in[4];
  float* out = (float*)d_out;

  char* ws = (char*)d_ws;
  u16* xb  = (u16*)(ws + 0);          // 16 MB
  u16* Wqb = (u16*)(ws + 16777216);
  u16* Wkb = (u16*)(ws + 18874368);
  u16* Wvb = (u16*)(ws + 20971520);
  u16* Wob = (u16*)(ws + 23068672);
  u16* Qb  = (u16*)(ws + 25165824);   // [B,H,S,DK]
  u16* Ksw = (u16*)(ws + 41943040);   // [B,H] x 32 tiles x swizzled 64x64
  u16* Vsw = (u16*)(ws + 58720256);   // [B,H] x 32 tiles x swizzled 64x64
  u16* Ab  = (u16*)(ws + 75497472);   // [B,S,DM]
  const size_t NEED = 92274688;
  if (ws_size < NEED) return;

  cvt_all<<<12288, 256, 0, stream>>>(x, Wq, Wk, Wv, Wo, xb, Wqb, Wkb, Wvb, Wob);

  dim3 gqkv(DM / 128, (BATCH * SEQ) / 128, 3);
  gemm_qkv<<<gqkv, 256, 0, stream>>>(xb, Wqb, Wkb, Wvb, Qb, Ksw, Vsw);

  dim3 gat(BATCH * NH, SEQ / 128);
  attn<<<gat, 256, 0, stream>>>(Qb, Ksw, Vsw, Ab);

  dim3 gout(DM / 128, (BATCH * SEQ) / 128);
  gemm_out<<<gout, 256, 0, stream>>>(Ab, Wob, out);
}

// Round 5
// 295.646 us; speedup vs baseline: 1.0459x; 1.0107x over previous
//
#include <hip/hip_runtime.h>

// Problem constants
#define BATCH 4
#define SEQ 2048
#define DM 1024
#define NH 16
#define DK 64

typedef unsigned short u16;
typedef unsigned int u32;
typedef __attribute__((ext_vector_type(8))) short bfrag;    // 8 bf16 (MFMA x32 A/B)
typedef __attribute__((ext_vector_type(4))) short bfrag4;   // 4 bf16 (MFMA x16 A/B)
typedef __attribute__((ext_vector_type(4))) float ffrag;    // 4 fp32 (MFMA C/D)

__device__ inline u16 f2bf(float f) {
  union { float f; u32 u; } v; v.f = f;
  u32 u = v.u;
  return (u16)((u + 0x7FFFu + ((u >> 16) & 1u)) >> 16);  // RNE
}
__device__ inline float bf2f(u16 u) {
  union { u32 u; float f; } v; v.u = ((u32)u) << 16;
  return v.f;
}
__device__ inline ffrag MFMA(bfrag a, bfrag b, ffrag c) {
  return __builtin_amdgcn_mfma_f32_16x16x32_bf16(a, b, c, 0, 0, 0);
}
// Device pass only (host __has_builtin is false — R4 lesson). Host gets a stub.
#if defined(__has_builtin)
#if __has_builtin(__builtin_amdgcn_mfma_f32_16x16x16bf16_1k)
#define HAVE_MFMA16 1
#endif
#endif
#if HAVE_MFMA16
__device__ inline ffrag MFMA16(bfrag4 a, bfrag4 b, ffrag c) {
  return __builtin_amdgcn_mfma_f32_16x16x16bf16_1k(a, b, c, 0, 0, 0);
}
#else
__device__ inline ffrag MFMA16(bfrag4 a, bfrag4 b, ffrag c) { return c; }  // host stub
#endif

// async global -> LDS, 16 bytes per lane (wave-uniform base + lane*16)
__device__ __forceinline__ void g2l16(const u16* g, u16* l) {
  __builtin_amdgcn_global_load_lds(
      (const __attribute__((address_space(1))) u16*)g,
      (__attribute__((address_space(3))) u16*)l, 16, 0, 0);
}

// ---------------- fused fp32 -> bf16 conversion (x + 4 weights, one launch).
// blocks [0,8192): x (8M floats). blocks [8192,12288): weights, 1024 blocks each.
__global__ __launch_bounds__(256) void cvt_all(
    const float* __restrict__ x,
    const float* __restrict__ a, const float* __restrict__ b,
    const float* __restrict__ c, const float* __restrict__ d,
    u16* __restrict__ ox,
    u16* __restrict__ oa, u16* __restrict__ ob,
    u16* __restrict__ oc, u16* __restrict__ od) {
  int blk = blockIdx.x;
  const float* in;
  u16* out;
  int i;
  if (blk < 8192) {
    in = x; out = ox; i = blk * 256 + threadIdx.x;
  } else {
    int wb = blk - 8192;
    int which = wb >> 10;
    in = which == 0 ? a : which == 1 ? b : which == 2 ? c : d;
    out = which == 0 ? oa : which == 1 ? ob : which == 2 ? oc : od;
    i = (wb & 1023) * 256 + threadIdx.x;
  }
  float4 v = ((const float4*)in)[i];
  union { u16 u[4]; uint2 dd; } o;
  o.u[0] = f2bf(v.x); o.u[1] = f2bf(v.y); o.u[2] = f2bf(v.z); o.u[3] = f2bf(v.w);
  ((uint2*)out)[i] = o.dd;
}

// ---------------- fused Q/K/V projection (R4: BK=64 + XOR-swizzled LDS).
// LDS tiles [128][64] bf16, linear dest for g2l16 (rule #21): the 16B slot
// within each 128B row is XOR-permuted on the GLOBAL SOURCE address
// (slot^(row&7) — per-thread constant) and the same involution is applied on
// the fragment ds_read address, so reads hit all 32 banks 2-way (free) instead
// of the 8-way conflict the old 64B-stride layout had. Barriers per K halved.
// z=0: Q row-layout [B,H,S,DK]. z=1: K swizzled per 64-kv tile. z=2: V^T
// swizzled (swapped operand roles). See epilogues.
__global__ __launch_bounds__(256) void gemm_qkv(
    const u16* __restrict__ xb,
    const u16* __restrict__ Wq, const u16* __restrict__ Wk,
    const u16* __restrict__ Wv,
    u16* __restrict__ Qb, u16* __restrict__ Ksw, u16* __restrict__ Vsw) {
  const int z = blockIdx.z;
  const u16* Bm = z == 0 ? Wq : z == 1 ? Wk : Wv;

  const int K = DM;
  const int bm = blockIdx.y * 128, bn = blockIdx.x * 128;
  __shared__ __align__(16) u16 As[128 * 64];
  __shared__ __align__(16) u16 Bs[128 * 64];
  const int tid = threadIdx.x;
  const int lane = tid & 63;
  const int w = tid >> 6;
  const int wr = w >> 1, wc = w & 1;
  const int l15 = lane & 15, quad = lane >> 4;
  // staging: call c covers rows [c*32, c*32+32); thread -> row c*32+(tid>>3),
  // LDS slot tid&7; source col slot^(row&7) (involution, per-thread constant)
  const int srow = tid >> 3;
  const int scol = (((tid & 7) ^ (srow & 7)) * 8);

  ffrag acc[4][4] = {};

  for (int k0 = 0; k0 < K; k0 += 64) {
    __syncthreads();
#pragma unroll
    for (int c = 0; c < 4; c++) {
      g2l16(&xb[(size_t)(bm + c * 32 + srow) * K + k0 + scol], &As[c * 2048 + tid * 8]);
      g2l16(&Bm[(size_t)(bn + c * 32 + srow) * K + k0 + scol], &Bs[c * 2048 + tid * 8]);
    }
    __syncthreads();
#pragma unroll
    for (int kk = 0; kk < 2; kk++) {
      bfrag af[4], bf[4];
      if (z < 2) {
#pragma unroll
        for (int i = 0; i < 4; i++)
          af[i] = *(const bfrag*)(&As[(wr * 64 + i * 16 + l15) * 64 +
                                      ((kk * 4 + quad) ^ (l15 & 7)) * 8]);
#pragma unroll
        for (int j = 0; j < 4; j++)
          bf[j] = *(const bfrag*)(&Bs[(wc * 64 + j * 16 + l15) * 64 +
                                      ((kk * 4 + quad) ^ (l15 & 7)) * 8]);
      } else {   // V: A = W (out-dims as m), B = x^T (tokens as n)
#pragma unroll
        for (int i = 0; i < 4; i++)
          af[i] = *(const bfrag*)(&Bs[(wr * 64 + i * 16 + l15) * 64 +
                                      ((kk * 4 + quad) ^ (l15 & 7)) * 8]);
#pragma unroll
        for (int j = 0; j < 4; j++)
          bf[j] = *(const bfrag*)(&As[(wc * 64 + j * 16 + l15) * 64 +
                                      ((kk * 4 + quad) ^ (l15 & 7)) * 8]);
      }
#pragma unroll
      for (int i = 0; i < 4; i++)
#pragma unroll
        for (int j = 0; j < 4; j++)
          acc[i][j] = MFMA(af[i], bf[j], acc[i][j]);
    }
  }

  if (z == 0) {
#pragma unroll
    for (int i = 0; i < 4; i++)
#pragma unroll
      for (int j = 0; j < 4; j++)
#pragma unroll
        for (int r = 0; r < 4; r++) {
          int m = bm + wr * 64 + i * 16 + quad * 4 + r;
          int n = bn + wc * 64 + j * 16 + l15;
          int b = m >> 11, s = m & 2047;
          int h = n >> 6, d = n & 63;
          Qb[(((size_t)(b * NH + h)) * SEQ + s) * DK + d] = f2bf(acc[i][j][r]);
        }
  } else if (z == 1) {
#pragma unroll
    for (int i = 0; i < 4; i++)
#pragma unroll
      for (int j = 0; j < 4; j++)
#pragma unroll
        for (int r = 0; r < 4; r++) {
          int m = bm + wr * 64 + i * 16 + quad * 4 + r;
          int n = bn + wc * 64 + j * 16 + l15;
          int b = m >> 11, s = m & 2047;
          int h = n >> 6, d = n & 63;
          size_t hb = (size_t)(b * NH + h) * (SEQ * DK);
          size_t off = hb + (size_t)(s >> 6) * 4096 +
              ((((s >> 4) & 3) * 2 + (d >> 5)) * 64 +
               ((d >> 3) & 3) * 16 + (s & 15)) * 8 + (d & 7);
          Ksw[off] = f2bf(acc[i][j][r]);
        }
  } else {
#pragma unroll
    for (int i = 0; i < 4; i++)
#pragma unroll
      for (int j = 0; j < 4; j++)
#pragma unroll
        for (int r = 0; r < 4; r++) {
          int n = bn + wr * 64 + i * 16 + quad * 4 + r;   // out-dim
          int m = bm + wc * 64 + j * 16 + l15;            // token
          int b = m >> 11, s = m & 2047;
          int h = n >> 6, d = n & 63;
          size_t hb = (size_t)(b * NH + h) * (SEQ * DK);
          size_t off = hb + (size_t)(s >> 6) * 4096 +
              ((((d >> 4) * 4 + ((s >> 4) & 3)) * 64 +
                ((s >> 2) & 3) * 16 + (d & 15)) * 4 + (s & 3));
          Vsw[off] = f2bf(acc[i][j][r]);
        }
  }
}

// ---------------- out projection GEMM (R4: BK=64 + XOR swizzle, as above)
__global__ __launch_bounds__(256) void gemm_out(
    const u16* __restrict__ Ab, const u16* __restrict__ Wo, float* __restrict__ C) {
  const int K = DM, N = DM;
  const int bm = blockIdx.y * 128, bn = blockIdx.x * 128;
  __shared__ __align__(16) u16 As[128 * 64];
  __shared__ __align__(16) u16 Bs[128 * 64];
  const int tid = threadIdx.x;
  const int lane = tid & 63;
  const int w = tid >> 6;
  const int wr = w >> 1, wc = w & 1;
  const int l15 = lane & 15, quad = lane >> 4;
  const int srow = tid >> 3;
  const int scol = (((tid & 7) ^ (srow & 7)) * 8);

  ffrag acc[4][4] = {};

  for (int k0 = 0; k0 < K; k0 += 64) {
    __syncthreads();
#pragma unroll
    for (int c = 0; c < 4; c++) {
      g2l16(&Ab[(size_t)(bm + c * 32 + srow) * K + k0 + scol], &As[c * 2048 + tid * 8]);
      g2l16(&Wo[(size_t)(bn + c * 32 + srow) * K + k0 + scol], &Bs[c * 2048 + tid * 8]);
    }
    __syncthreads();
#pragma unroll
    for (int kk = 0; kk < 2; kk++) {
      bfrag af[4], bf[4];
#pragma unroll
      for (int i = 0; i < 4; i++)
        af[i] = *(const bfrag*)(&As[(wr * 64 + i * 16 + l15) * 64 +
                                    ((kk * 4 + quad) ^ (l15 & 7)) * 8]);
#pragma unroll
      for (int j = 0; j < 4; j++)
        bf[j] = *(const bfrag*)(&Bs[(wc * 64 + j * 16 + l15) * 64 +
                                    ((kk * 4 + quad) ^ (l15 & 7)) * 8]);
#pragma unroll
      for (int i = 0; i < 4; i++)
#pragma unroll
        for (int j = 0; j < 4; j++)
          acc[i][j] = MFMA(af[i], bf[j], acc[i][j]);
    }
  }

#pragma unroll
  for (int i = 0; i < 4; i++)
#pragma unroll
    for (int j = 0; j < 4; j++)
#pragma unroll
      for (int r = 0; r < 4; r++) {
        int m = bm + wr * 64 + i * 16 + quad * 4 + r;
        int n = bn + wc * 64 + j * 16 + l15;
        C[(size_t)m * N + n] = acc[i][j][r];
      }
}

// ---------------- Flash attention (R5: R1's proven compute body — VALU lsum,
// VGPR ~56 — plus the R4 XCD-locality transpose (blockIdx.x = head; FETCH
// 139->40MB proven) and T5 setprio. R4's MFMA-lsum is reverted: it raised
// VGPR 56->72 and serialized pb->Ls on the MFMA chain for a net -7µs.
// Each wave owns two 16-q blocks. S^T = K.Q^T (x32 MFMA); P truncated to
// bf16 via bit-ops; lsum accumulates the same truncated values on the VALU.
// O^T += V^T.P^T (x16 MFMA). K/V staged via g2l16 DMA from swizzled global
// into double buffers; compute reads ONLY LDS (single per-tile barrier; DMA
// of tile t+1 overlaps the whole compute(t)).
__global__ __launch_bounds__(256) void attn(
    const u16* __restrict__ Qb, const u16* __restrict__ Ksw,
    const u16* __restrict__ Vsw, u16* __restrict__ Ab) {
  const int bh = blockIdx.x;
  const int b = bh >> 4, h = bh & 15;
  const int qbase = blockIdx.y * 128;
  const int tid = threadIdx.x;
  const int w = tid >> 6, lane = tid & 63;
  const int l15 = lane & 15, quad = lane >> 4;

  __shared__ __align__(16) u16 Kt[2][4096];   // swizzled 64x64 K tile, dbuf
  __shared__ __align__(16) u16 Vt[2][4096];   // swizzled 64x64 V tile, dbuf

  const size_t hbase = (size_t)bh * SEQ * DK;

  // Q fragments (B-operand: n=q=l15, k=d=quad*8+e) scaled by 0.125*log2e
  const float qscale = 0.125f * 1.4426950408889634f;
  bfrag q[2][2];
#pragma unroll
  for (int i = 0; i < 2; i++)
#pragma unroll
    for (int kk = 0; kk < 2; kk++) {
      bfrag t = *(const bfrag*)(&Qb[hbase +
          (size_t)(qbase + w * 32 + i * 16 + l15) * DK + kk * 32 + quad * 8]);
#pragma unroll
      for (int e = 0; e < 8; e++)
        q[i][kk][e] = (short)f2bf(bf2f((u16)t[e]) * qscale);
    }

  ffrag O[4][2] = {};      // O^T accs: [d-block][q-block]
  float lsum[2] = {0.f, 0.f};

  // prefetch tile 0 (K: 8KB = 2 DMA calls; V: 8KB = 2 DMA calls)
  {
    const u16* ks = &Ksw[hbase];
    const u16* vs = &Vsw[hbase];
    g2l16(&ks[tid * 8], &Kt[0][tid * 8]);
    g2l16(&ks[2048 + tid * 8], &Kt[0][2048 + tid * 8]);
    g2l16(&vs[tid * 8], &Vt[0][tid * 8]);
    g2l16(&vs[2048 + tid * 8], &Vt[0][2048 + tid * 8]);
  }

  for (int t = 0; t < SEQ / 64; t++) {
    const int buf = t & 1;
    __syncthreads();   // DMA for tile t complete; prior reads of buf^1 done
    if (t + 1 < SEQ / 64) {
      const u16* ks = &Ksw[hbase + (size_t)(t + 1) * 4096];
      const u16* vs = &Vsw[hbase + (size_t)(t + 1) * 4096];
      g2l16(&ks[tid * 8], &Kt[buf ^ 1][tid * 8]);
      g2l16(&ks[2048 + tid * 8], &Kt[buf ^ 1][2048 + tid * 8]);
      g2l16(&vs[tid * 8], &Vt[buf ^ 1][tid * 8]);
      g2l16(&vs[2048 + tid * 8], &Vt[buf ^ 1][2048 + tid * 8]);
    }

    __builtin_amdgcn_s_setprio(1);
    bfrag4 pb[4][2];
#pragma unroll
    for (int j = 0; j < 4; j++) {     // kv 16-block
      bfrag k0f = *(const bfrag*)(&Kt[buf][((j * 2 + 0) * 64 + lane) * 8]);
      bfrag k1f = *(const bfrag*)(&Kt[buf][((j * 2 + 1) * 64 + lane) * 8]);
#pragma unroll
      for (int i = 0; i < 2; i++) {   // q 16-block
        ffrag z = {};
        z = MFMA(k0f, q[i][0], z);
        z = MFMA(k1f, q[i][1], z);    // S^T block: lane (q=l15, s=quad*4+r)
        u32 u[4]; float ts = 0.f;
#pragma unroll
        for (int r = 0; r < 4; r++) {
          float p = __builtin_amdgcn_exp2f(z[r]);
          u[r] = __float_as_uint(p);
          ts += __uint_as_float(u[r] & 0xffff0000u);
        }
        lsum[i] += ts;
        union { u32 d[2]; bfrag4 v; } pk;
        pk.d[0] = (u[1] & 0xffff0000u) | (u[0] >> 16);
        pk.d[1] = (u[3] & 0xffff0000u) | (u[2] >> 16);
        pb[j][i] = pk.v;
      }
    }

    // O^T += V^T . P^T : A-frags lane-linear b64 from swizzled V tile
#pragma unroll
    for (int j = 0; j < 4; j++)
#pragma unroll
      for (int db = 0; db < 4; db++) {
        bfrag4 vf = *(const bfrag4*)(&Vt[buf][((db * 4 + j) * 64 + lane) * 4]);
        O[db][0] = MFMA16(vf, pb[j][0], O[db][0]);
        O[db][1] = MFMA16(vf, pb[j][1], O[db][1]);
      }
    __builtin_amdgcn_s_setprio(0);
  }

  // reduce lsum across the 4 quads (same q=l15)
  float rl[2];
#pragma unroll
  for (int i = 0; i < 2; i++) {
    float s = lsum[i];
    s += __shfl_xor(s, 16);
    s += __shfl_xor(s, 32);
    rl[i] = 1.0f / s;
  }

  // O^T C-layout: lane holds q=l15, d=quad*4+r. Pack 4 d (8B) per store.
  const size_t obase = ((size_t)b * SEQ) * DM + (size_t)h * DK;
#pragma unroll
  for (int db = 0; db < 4; db++)
#pragma unroll
    for (int i = 0; i < 2; i++) {
      int s = qbase + w * 32 + i * 16 + l15;
      union { u16 u[4]; uint2 d; } o;
#pragma unroll
      for (int r = 0; r < 4; r++) o.u[r] = f2bf(O[db][i][r] * rl[i]);
      *(uint2*)(&Ab[obase + (size_t)s * DM + db * 16 + quad * 4]) = o.d;
    }
}

extern "C" void kernel_launch(void* const* d_in, const int* in_sizes, int n_in,
                              void* d_out, int out_size, void* d_ws, size_t ws_size,
                              hipStream_t stream) {
  const float* x  = (const float*)d_in[0];
  const float* Wq = (const float*)d_in[1];
  const float* Wk = (const float*)d_in[2];
  const float* Wv = (const float*)d_in[3];
  const float* Wo = (const float*)d_in[4];
  float* out = (float*)d_out;

  char* ws = (char*)d_ws;
  u16* xb  = (u16*)(ws + 0);          // 16 MB
  u16* Wqb = (u16*)(ws + 16777216);
  u16* Wkb = (u16*)(ws + 18874368);
  u16* Wvb = (u16*)(ws + 20971520);
  u16* Wob = (u16*)(ws + 23068672);
  u16* Qb  = (u16*)(ws + 25165824);   // [B,H,S,DK]
  u16* Ksw = (u16*)(ws + 41943040);   // [B,H] x 32 tiles x swizzled 64x64
  u16* Vsw = (u16*)(ws + 58720256);   // [B,H] x 32 tiles x swizzled 64x64
  u16* Ab  = (u16*)(ws + 75497472);   // [B,S,DM]
  const size_t NEED = 92274688;
  if (ws_size < NEED) return;

  cvt_all<<<12288, 256, 0, stream>>>(x, Wq, Wk, Wv, Wo, xb, Wqb, Wkb, Wvb, Wob);

  dim3 gqkv(DM / 128, (BATCH * SEQ) / 128, 3);
  gemm_qkv<<<gqkv, 256, 0, stream>>>(xb, Wqb, Wkb, Wvb, Qb, Ksw, Vsw);

  dim3 gat(BATCH * NH, SEQ / 128);
  attn<<<gat, 256, 0, stream>>>(Qb, Ksw, Vsw, Ab);

  dim3 gout(DM / 128, (BATCH * SEQ) / 128);
  gemm_out<<<gout, 256, 0, stream>>>(Ab, Wob, out);
}

// Round 6
// 265.514 us; speedup vs baseline: 1.1646x; 1.1135x over previous
//
#include <hip/hip_runtime.h>

// Problem constants
#define BATCH 4
#define SEQ 2048
#define DM 1024
#define NH 16
#define DK 64

typedef unsigned short u16;
typedef unsigned int u32;
typedef __attribute__((ext_vector_type(8))) short bfrag;    // 8 bf16 (MFMA x32 A/B)
typedef __attribute__((ext_vector_type(4))) short bfrag4;   // 4 bf16 (MFMA x16 A/B)
typedef __attribute__((ext_vector_type(4))) float ffrag;    // 4 fp32 (MFMA C/D)

__device__ inline u16 f2bf(float f) {
  union { float f; u32 u; } v; v.f = f;
  u32 u = v.u;
  return (u16)((u + 0x7FFFu + ((u >> 16) & 1u)) >> 16);  // RNE
}
__device__ inline float bf2f(u16 u) {
  union { u32 u; float f; } v; v.u = ((u32)u) << 16;
  return v.f;
}
__device__ inline ffrag MFMA(bfrag a, bfrag b, ffrag c) {
  return __builtin_amdgcn_mfma_f32_16x16x32_bf16(a, b, c, 0, 0, 0);
}
// Device pass only (host __has_builtin is false — R4 lesson). Host gets a stub.
#if defined(__has_builtin)
#if __has_builtin(__builtin_amdgcn_mfma_f32_16x16x16bf16_1k)
#define HAVE_MFMA16 1
#endif
#endif
#if HAVE_MFMA16
__device__ inline ffrag MFMA16(bfrag4 a, bfrag4 b, ffrag c) {
  return __builtin_amdgcn_mfma_f32_16x16x16bf16_1k(a, b, c, 0, 0, 0);
}
#else
__device__ inline ffrag MFMA16(bfrag4 a, bfrag4 b, ffrag c) { return c; }  // host stub
#endif

// async global -> LDS, 16 bytes per lane (wave-uniform base + lane*16)
__device__ __forceinline__ void g2l16(const u16* g, u16* l) {
  __builtin_amdgcn_global_load_lds(
      (const __attribute__((address_space(1))) u16*)g,
      (__attribute__((address_space(3))) u16*)l, 16, 0, 0);
}

// ---------------- fused fp32 -> bf16 conversion (x + 4 weights, one launch).
// blocks [0,8192): x (8M floats). blocks [8192,12288): weights, 1024 blocks each.
__global__ __launch_bounds__(256) void cvt_all(
    const float* __restrict__ x,
    const float* __restrict__ a, const float* __restrict__ b,
    const float* __restrict__ c, const float* __restrict__ d,
    u16* __restrict__ ox,
    u16* __restrict__ oa, u16* __restrict__ ob,
    u16* __restrict__ oc, u16* __restrict__ od) {
  int blk = blockIdx.x;
  const float* in;
  u16* out;
  int i;
  if (blk < 8192) {
    in = x; out = ox; i = blk * 256 + threadIdx.x;
  } else {
    int wb = blk - 8192;
    int which = wb >> 10;
    in = which == 0 ? a : which == 1 ? b : which == 2 ? c : d;
    out = which == 0 ? oa : which == 1 ? ob : which == 2 ? oc : od;
    i = (wb & 1023) * 256 + threadIdx.x;
  }
  float4 v = ((const float4*)in)[i];
  union { u16 u[4]; uint2 dd; } o;
  o.u[0] = f2bf(v.x); o.u[1] = f2bf(v.y); o.u[2] = f2bf(v.z); o.u[3] = f2bf(v.w);
  ((uint2*)out)[i] = o.dd;
}

// ---------------- fused Q/K/V projection (R6: XCD-ownership remap).
// 1-D grid, decode so XCD k (= bid&7, per m157's verified id%8 mapping) owns
// bm-panels y in [8k, 8k+8) for ALL (bn, z): per-XCD working set becomes
// A 2MB (L2-resident) + weights 6MB cycled once, vs streaming all 16MB of xb
// 3x per XCD under the default mapping (~5x less L2-miss traffic).
// LDS tiles [128][64] bf16, BK=64, linear dest for g2l16 (rule #21): 16B slot
// within each 128B row XOR-permuted on the GLOBAL SOURCE address and the same
// involution on the fragment ds_read address (2-way banks, free).
// z=0: Q row-layout [B,H,S,DK]. z=1: K swizzled per 64-kv tile. z=2: V^T
// swizzled (swapped operand roles). See epilogues.
__global__ __launch_bounds__(256) void gemm_qkv(
    const u16* __restrict__ xb,
    const u16* __restrict__ Wq, const u16* __restrict__ Wk,
    const u16* __restrict__ Wv,
    u16* __restrict__ Qb, u16* __restrict__ Ksw, u16* __restrict__ Vsw) {
  const int bid = blockIdx.x;
  const int xcd = bid & 7, s8 = bid >> 3;     // 192 blocks per XCD
  const int ym = (xcd << 3) | (s8 & 7);       // bm-panel in [8*xcd, 8*xcd+8)
  const int xn = (s8 >> 3) & 7;
  const int z = s8 >> 6;
  const u16* Bm = z == 0 ? Wq : z == 1 ? Wk : Wv;

  const int K = DM;
  const int bm = ym * 128, bn = xn * 128;
  __shared__ __align__(16) u16 As[128 * 64];
  __shared__ __align__(16) u16 Bs[128 * 64];
  const int tid = threadIdx.x;
  const int lane = tid & 63;
  const int w = tid >> 6;
  const int wr = w >> 1, wc = w & 1;
  const int l15 = lane & 15, quad = lane >> 4;
  // staging: call c covers rows [c*32, c*32+32); thread -> row c*32+(tid>>3),
  // LDS slot tid&7; source col slot^(row&7) (involution, per-thread constant)
  const int srow = tid >> 3;
  const int scol = (((tid & 7) ^ (srow & 7)) * 8);

  ffrag acc[4][4] = {};

  for (int k0 = 0; k0 < K; k0 += 64) {
    __syncthreads();
#pragma unroll
    for (int c = 0; c < 4; c++) {
      g2l16(&xb[(size_t)(bm + c * 32 + srow) * K + k0 + scol], &As[c * 2048 + tid * 8]);
      g2l16(&Bm[(size_t)(bn + c * 32 + srow) * K + k0 + scol], &Bs[c * 2048 + tid * 8]);
    }
    __syncthreads();
#pragma unroll
    for (int kk = 0; kk < 2; kk++) {
      bfrag af[4], bf[4];
      if (z < 2) {
#pragma unroll
        for (int i = 0; i < 4; i++)
          af[i] = *(const bfrag*)(&As[(wr * 64 + i * 16 + l15) * 64 +
                                      ((kk * 4 + quad) ^ (l15 & 7)) * 8]);
#pragma unroll
        for (int j = 0; j < 4; j++)
          bf[j] = *(const bfrag*)(&Bs[(wc * 64 + j * 16 + l15) * 64 +
                                      ((kk * 4 + quad) ^ (l15 & 7)) * 8]);
      } else {   // V: A = W (out-dims as m), B = x^T (tokens as n)
#pragma unroll
        for (int i = 0; i < 4; i++)
          af[i] = *(const bfrag*)(&Bs[(wr * 64 + i * 16 + l15) * 64 +
                                      ((kk * 4 + quad) ^ (l15 & 7)) * 8]);
#pragma unroll
        for (int j = 0; j < 4; j++)
          bf[j] = *(const bfrag*)(&As[(wc * 64 + j * 16 + l15) * 64 +
                                      ((kk * 4 + quad) ^ (l15 & 7)) * 8]);
      }
#pragma unroll
      for (int i = 0; i < 4; i++)
#pragma unroll
        for (int j = 0; j < 4; j++)
          acc[i][j] = MFMA(af[i], bf[j], acc[i][j]);
    }
  }

  if (z == 0) {
#pragma unroll
    for (int i = 0; i < 4; i++)
#pragma unroll
      for (int j = 0; j < 4; j++)
#pragma unroll
        for (int r = 0; r < 4; r++) {
          int m = bm + wr * 64 + i * 16 + quad * 4 + r;
          int n = bn + wc * 64 + j * 16 + l15;
          int b = m >> 11, s = m & 2047;
          int h = n >> 6, d = n & 63;
          Qb[(((size_t)(b * NH + h)) * SEQ + s) * DK + d] = f2bf(acc[i][j][r]);
        }
  } else if (z == 1) {
#pragma unroll
    for (int i = 0; i < 4; i++)
#pragma unroll
      for (int j = 0; j < 4; j++)
#pragma unroll
        for (int r = 0; r < 4; r++) {
          int m = bm + wr * 64 + i * 16 + quad * 4 + r;
          int n = bn + wc * 64 + j * 16 + l15;
          int b = m >> 11, s = m & 2047;
          int h = n >> 6, d = n & 63;
          size_t hb = (size_t)(b * NH + h) * (SEQ * DK);
          size_t off = hb + (size_t)(s >> 6) * 4096 +
              ((((s >> 4) & 3) * 2 + (d >> 5)) * 64 +
               ((d >> 3) & 3) * 16 + (s & 15)) * 8 + (d & 7);
          Ksw[off] = f2bf(acc[i][j][r]);
        }
  } else {
#pragma unroll
    for (int i = 0; i < 4; i++)
#pragma unroll
      for (int j = 0; j < 4; j++)
#pragma unroll
        for (int r = 0; r < 4; r++) {
          int n = bn + wr * 64 + i * 16 + quad * 4 + r;   // out-dim
          int m = bm + wc * 64 + j * 16 + l15;            // token
          int b = m >> 11, s = m & 2047;
          int h = n >> 6, d = n & 63;
          size_t hb = (size_t)(b * NH + h) * (SEQ * DK);
          size_t off = hb + (size_t)(s >> 6) * 4096 +
              ((((d >> 4) * 4 + ((s >> 4) & 3)) * 64 +
                ((s >> 2) & 3) * 16 + (d & 15)) * 4 + (s & 3));
          Vsw[off] = f2bf(acc[i][j][r]);
        }
  }
}

// ---------------- out projection GEMM (R6: XCD-ownership remap; per-XCD
// working set = 8 A-panels (2MB) + all of Wo (2MB) -> both L2-resident).
__global__ __launch_bounds__(256) void gemm_out(
    const u16* __restrict__ Ab, const u16* __restrict__ Wo, float* __restrict__ C) {
  const int K = DM, N = DM;
  const int bid = blockIdx.x;
  const int xcd = bid & 7, s8 = bid >> 3;     // 64 blocks per XCD
  const int ym = (xcd << 3) | (s8 & 7);
  const int xn = s8 >> 3;
  const int bm = ym * 128, bn = xn * 128;
  __shared__ __align__(16) u16 As[128 * 64];
  __shared__ __align__(16) u16 Bs[128 * 64];
  const int tid = threadIdx.x;
  const int lane = tid & 63;
  const int w = tid >> 6;
  const int wr = w >> 1, wc = w & 1;
  const int l15 = lane & 15, quad = lane >> 4;
  const int srow = tid >> 3;
  const int scol = (((tid & 7) ^ (srow & 7)) * 8);

  ffrag acc[4][4] = {};

  for (int k0 = 0; k0 < K; k0 += 64) {
    __syncthreads();
#pragma unroll
    for (int c = 0; c < 4; c++) {
      g2l16(&Ab[(size_t)(bm + c * 32 + srow) * K + k0 + scol], &As[c * 2048 + tid * 8]);
      g2l16(&Wo[(size_t)(bn + c * 32 + srow) * K + k0 + scol], &Bs[c * 2048 + tid * 8]);
    }
    __syncthreads();
#pragma unroll
    for (int kk = 0; kk < 2; kk++) {
      bfrag af[4], bf[4];
#pragma unroll
      for (int i = 0; i < 4; i++)
        af[i] = *(const bfrag*)(&As[(wr * 64 + i * 16 + l15) * 64 +
                                    ((kk * 4 + quad) ^ (l15 & 7)) * 8]);
#pragma unroll
      for (int j = 0; j < 4; j++)
        bf[j] = *(const bfrag*)(&Bs[(wc * 64 + j * 16 + l15) * 64 +
                                    ((kk * 4 + quad) ^ (l15 & 7)) * 8]);
#pragma unroll
      for (int i = 0; i < 4; i++)
#pragma unroll
        for (int j = 0; j < 4; j++)
          acc[i][j] = MFMA(af[i], bf[j], acc[i][j]);
    }
  }

#pragma unroll
  for (int i = 0; i < 4; i++)
#pragma unroll
    for (int j = 0; j < 4; j++)
#pragma unroll
      for (int r = 0; r < 4; r++) {
        int m = bm + wr * 64 + i * 16 + quad * 4 + r;
        int n = bn + wc * 64 + j * 16 + l15;
        C[(size_t)m * N + n] = acc[i][j][r];
      }
}

// ---------------- Flash attention (R6: R5 body + v_perm bf16 packing).
// attn is issue-bound (VALU 59% + MFMA 41%); the per-fragment pack
// (2 shifts + 2 ands + 2 ors) becomes 2 v_perm_b32 (sel 0x07060302:
// {hi.b3,hi.b2,lo.b3,lo.b2} = (hi&0xffff0000)|(lo>>16)). lsum keeps the
// AND+ADD truncated form (bias-cancellation with PV's truncated P).
// XCD-locality transpose (blockIdx.x = head) + T5 setprio retained.
__global__ __launch_bounds__(256) void attn(
    const u16* __restrict__ Qb, const u16* __restrict__ Ksw,
    const u16* __restrict__ Vsw, u16* __restrict__ Ab) {
  const int bh = blockIdx.x;
  const int b = bh >> 4, h = bh & 15;
  const int qbase = blockIdx.y * 128;
  const int tid = threadIdx.x;
  const int w = tid >> 6, lane = tid & 63;
  const int l15 = lane & 15, quad = lane >> 4;

  __shared__ __align__(16) u16 Kt[2][4096];   // swizzled 64x64 K tile, dbuf
  __shared__ __align__(16) u16 Vt[2][4096];   // swizzled 64x64 V tile, dbuf

  const size_t hbase = (size_t)bh * SEQ * DK;

  // Q fragments (B-operand: n=q=l15, k=d=quad*8+e) scaled by 0.125*log2e
  const float qscale = 0.125f * 1.4426950408889634f;
  bfrag q[2][2];
#pragma unroll
  for (int i = 0; i < 2; i++)
#pragma unroll
    for (int kk = 0; kk < 2; kk++) {
      bfrag t = *(const bfrag*)(&Qb[hbase +
          (size_t)(qbase + w * 32 + i * 16 + l15) * DK + kk * 32 + quad * 8]);
#pragma unroll
      for (int e = 0; e < 8; e++)
        q[i][kk][e] = (short)f2bf(bf2f((u16)t[e]) * qscale);
    }

  ffrag O[4][2] = {};      // O^T accs: [d-block][q-block]
  float lsum[2] = {0.f, 0.f};

  // prefetch tile 0 (K: 8KB = 2 DMA calls; V: 8KB = 2 DMA calls)
  {
    const u16* ks = &Ksw[hbase];
    const u16* vs = &Vsw[hbase];
    g2l16(&ks[tid * 8], &Kt[0][tid * 8]);
    g2l16(&ks[2048 + tid * 8], &Kt[0][2048 + tid * 8]);
    g2l16(&vs[tid * 8], &Vt[0][tid * 8]);
    g2l16(&vs[2048 + tid * 8], &Vt[0][2048 + tid * 8]);
  }

  for (int t = 0; t < SEQ / 64; t++) {
    const int buf = t & 1;
    __syncthreads();   // DMA for tile t complete; prior reads of buf^1 done
    if (t + 1 < SEQ / 64) {
      const u16* ks = &Ksw[hbase + (size_t)(t + 1) * 4096];
      const u16* vs = &Vsw[hbase + (size_t)(t + 1) * 4096];
      g2l16(&ks[tid * 8], &Kt[buf ^ 1][tid * 8]);
      g2l16(&ks[2048 + tid * 8], &Kt[buf ^ 1][2048 + tid * 8]);
      g2l16(&vs[tid * 8], &Vt[buf ^ 1][tid * 8]);
      g2l16(&vs[2048 + tid * 8], &Vt[buf ^ 1][2048 + tid * 8]);
    }

    __builtin_amdgcn_s_setprio(1);
    bfrag4 pb[4][2];
#pragma unroll
    for (int j = 0; j < 4; j++) {     // kv 16-block
      bfrag k0f = *(const bfrag*)(&Kt[buf][((j * 2 + 0) * 64 + lane) * 8]);
      bfrag k1f = *(const bfrag*)(&Kt[buf][((j * 2 + 1) * 64 + lane) * 8]);
#pragma unroll
      for (int i = 0; i < 2; i++) {   // q 16-block
        ffrag z = {};
        z = MFMA(k0f, q[i][0], z);
        z = MFMA(k1f, q[i][1], z);    // S^T block: lane (q=l15, s=quad*4+r)
        u32 u[4]; float ts = 0.f;
#pragma unroll
        for (int r = 0; r < 4; r++) {
          float p = __builtin_amdgcn_exp2f(z[r]);
          u[r] = __float_as_uint(p);
          ts += __uint_as_float(u[r] & 0xffff0000u);
        }
        lsum[i] += ts;
        union { u32 d[2]; bfrag4 v; } pk;
        pk.d[0] = __builtin_amdgcn_perm(u[1], u[0], 0x07060302u);
        pk.d[1] = __builtin_amdgcn_perm(u[3], u[2], 0x07060302u);
        pb[j][i] = pk.v;
      }
    }

    // O^T += V^T . P^T : A-frags lane-linear b64 from swizzled V tile
#pragma unroll
    for (int j = 0; j < 4; j++)
#pragma unroll
      for (int db = 0; db < 4; db++) {
        bfrag4 vf = *(const bfrag4*)(&Vt[buf][((db * 4 + j) * 64 + lane) * 4]);
        O[db][0] = MFMA16(vf, pb[j][0], O[db][0]);
        O[db][1] = MFMA16(vf, pb[j][1], O[db][1]);
      }
    __builtin_amdgcn_s_setprio(0);
  }

  // reduce lsum across the 4 quads (same q=l15)
  float rl[2];
#pragma unroll
  for (int i = 0; i < 2; i++) {
    float s = lsum[i];
    s += __shfl_xor(s, 16);
    s += __shfl_xor(s, 32);
    rl[i] = 1.0f / s;
  }

  // O^T C-layout: lane holds q=l15, d=quad*4+r. Pack 4 d (8B) per store.
  const size_t obase = ((size_t)b * SEQ) * DM + (size_t)h * DK;
#pragma unroll
  for (int db = 0; db < 4; db++)
#pragma unroll
    for (int i = 0; i < 2; i++) {
      int s = qbase + w * 32 + i * 16 + l15;
      union { u16 u[4]; uint2 d; } o;
#pragma unroll
      for (int r = 0; r < 4; r++) o.u[r] = f2bf(O[db][i][r] * rl[i]);
      *(uint2*)(&Ab[obase + (size_t)s * DM + db * 16 + quad * 4]) = o.d;
    }
}

extern "C" void kernel_launch(void* const* d_in, const int* in_sizes, int n_in,
                              void* d_out, int out_size, void* d_ws, size_t ws_size,
                              hipStream_t stream) {
  const float* x  = (const float*)d_in[0];
  const float* Wq = (const float*)d_in[1];
  const float* Wk = (const float*)d_in[2];
  const float* Wv = (const float*)d_in[3];
  const float* Wo = (const float*)d_in[4];
  float* out = (float*)d_out;

  char* ws = (char*)d_ws;
  u16* xb  = (u16*)(ws + 0);          // 16 MB
  u16* Wqb = (u16*)(ws + 16777216);
  u16* Wkb = (u16*)(ws + 18874368);
  u16* Wvb = (u16*)(ws + 20971520);
  u16* Wob = (u16*)(ws + 23068672);
  u16* Qb  = (u16*)(ws + 25165824);   // [B,H,S,DK]
  u16* Ksw = (u16*)(ws + 41943040);   // [B,H] x 32 tiles x swizzled 64x64
  u16* Vsw = (u16*)(ws + 58720256);   // [B,H] x 32 tiles x swizzled 64x64
  u16* Ab  = (u16*)(ws + 75497472);   // [B,S,DM]
  const size_t NEED = 92274688;
  if (ws_size < NEED) return;

  cvt_all<<<12288, 256, 0, stream>>>(x, Wq, Wk, Wv, Wo, xb, Wqb, Wkb, Wvb, Wob);

  gemm_qkv<<<1536, 256, 0, stream>>>(xb, Wqb, Wkb, Wvb, Qb, Ksw, Vsw);

  dim3 gat(BATCH * NH, SEQ / 128);
  attn<<<gat, 256, 0, stream>>>(Qb, Ksw, Vsw, Ab);

  gemm_out<<<512, 256, 0, stream>>>(Ab, Wob, out);
}